// Round 16
// baseline (137.792 us; speedup 1.0000x reference)
//
#include <hip/hip_runtime.h>
#include <hip/hip_bf16.h>

// Problem constants (fixed by reference)
#define N_NODES 2048
#define EMBED   32
#define B_BATCH 16
#define INP     32
#define OUTC    32
#define CHEB_K  3
#define NCOL    512

// R16 = R15 (130.8us) + k_v broadcast restructure:
//  512-thread blocks, grid (8 n-tiles x 256, 32 m-chunks) = 2048 waves
//  (unchanged). Wave owns d4 group; 64 lanes own 4 n each -> per-m Us read
//  is a SAME-ADDRESS LDS broadcast (1 access/wave vs 64x16B): block LDS
//  reads 1MB -> 8KB. R15 evidence: k_v was LDS-read-bound (512MB/pass at
//  69TB/s ~ 7us), not global-latency-bound.
// LAW (R13): never trade total waves for traffic (2048 waves preserved).
// LAW (R9/R11): no bulk global fp32 atomicAdd (uncached 32B RMW at MALL).
// LAW (R7-R9): no software grid barrier; dispatch boundaries are cheaper.
// Fixed tax: harness re-poison fill of 268MB ws (~43us).

// ---------------------------------------------------------------------------
// k_gram: 64x64 tiles. EhatT[j][i] = bf16(exp(exp(-g*dist(i,j)))*drop[i][j]),
// Psum[jt][i] = fp32 row-sum partials (pre-drop). Block (0,0) zeroes out.
// ---------------------------------------------------------------------------
__global__ __launch_bounds__(256) void k_gram(
    const float* __restrict__ adj, const float* __restrict__ gammap,
    const float* __restrict__ drop,
    __hip_bfloat16* __restrict__ EhatT, float* __restrict__ Psum,
    float* __restrict__ out)
{
    __shared__ float ai[64][36];            // [row i][k]
    __shared__ float ajT[32][68];           // [k][col j]
    __shared__ float nI[64], nJ[64];
    __shared__ float rm[64][17];
    __shared__ __hip_bfloat16 tS[64][72];   // [local j][local i]
    const int tid = threadIdx.x;
    if (blockIdx.x == 0 && blockIdx.y == 0) {
        out[tid] = 0.f; out[256 + tid] = 0.f;
    }
    const int j0 = blockIdx.x * 64;
    const int i0 = blockIdx.y * 64;
    const float gamma = gammap[0];

#pragma unroll
    for (int r = 0; r < 8; r++) {
        const int idx = r * 256 + tid;           // 0..2047
        ai[idx >> 5][idx & 31]  = adj[(size_t)(i0 + (idx >> 5)) * EMBED + (idx & 31)];
        ajT[idx & 31][idx >> 5] = adj[(size_t)(j0 + (idx >> 5)) * EMBED + (idx & 31)];
    }
    __syncthreads();
    if (tid < 64) {
        float s = 0.f;
#pragma unroll
        for (int k = 0; k < 32; k++) { const float v = ai[tid][k]; s += v * v; }
        nI[tid] = s;
    } else if (tid < 128) {
        const int col = tid - 64;
        float s = 0.f;
#pragma unroll
        for (int k = 0; k < 32; k++) { const float v = ajT[k][col]; s += v * v; }
        nJ[col] = s;
    }
    __syncthreads();

    const int ti = tid >> 4, tj = tid & 15;
    float acc[4][4] = {};
#pragma unroll
    for (int k4 = 0; k4 < 8; k4++) {
        float4 a4[4], b4[4];
#pragma unroll
        for (int r = 0; r < 4; r++) a4[r] = *(const float4*)&ai[ti * 4 + r][k4 * 4];
#pragma unroll
        for (int kk = 0; kk < 4; kk++) b4[kk] = *(const float4*)&ajT[k4 * 4 + kk][tj * 4];
#pragma unroll
        for (int r = 0; r < 4; r++) {
            acc[r][0] += a4[r].x * b4[0].x + a4[r].y * b4[1].x + a4[r].z * b4[2].x + a4[r].w * b4[3].x;
            acc[r][1] += a4[r].x * b4[0].y + a4[r].y * b4[1].y + a4[r].z * b4[2].y + a4[r].w * b4[3].y;
            acc[r][2] += a4[r].x * b4[0].z + a4[r].y * b4[1].z + a4[r].z * b4[2].z + a4[r].w * b4[3].z;
            acc[r][3] += a4[r].x * b4[0].w + a4[r].y * b4[1].w + a4[r].z * b4[2].w + a4[r].w * b4[3].w;
        }
    }
#pragma unroll
    for (int r = 0; r < 4; r++) {
        const int i = i0 + ti * 4 + r;
        const float ni = nI[ti * 4 + r];
        float e[4];
#pragma unroll
        for (int c = 0; c < 4; c++) {
            const float dist = ni + nJ[tj * 4 + c] - 2.f * acc[r][c];
            e[c] = __expf(__expf(-gamma * dist));
        }
        rm[ti * 4 + r][tj] = e[0] + e[1] + e[2] + e[3];
        const float4 dr = *(const float4*)&drop[(size_t)i * N_NODES + j0 + tj * 4];
        tS[tj * 4 + 0][ti * 4 + r] = __float2bfloat16(e[0] * dr.x);
        tS[tj * 4 + 1][ti * 4 + r] = __float2bfloat16(e[1] * dr.y);
        tS[tj * 4 + 2][ti * 4 + r] = __float2bfloat16(e[2] * dr.z);
        tS[tj * 4 + 3][ti * 4 + r] = __float2bfloat16(e[3] * dr.w);
    }
    __syncthreads();
    {   // coalesced transposed write-out: 4 threads per row j, 16 cols each
        const int jr = tid >> 2;            // 0..63
        const int ic = (tid & 3) * 16;      // 0,16,32,48
        const uint4* src = (const uint4*)&tS[jr][ic];
        uint4* dst = (uint4*)(EhatT + (size_t)(j0 + jr) * N_NODES + i0 + ic);
        dst[0] = src[0];
        dst[1] = src[1];
    }
    if (tid < 64) {
        float s = 0.f;
#pragma unroll
        for (int t = 0; t < 16; t++) s += rm[tid][t];
        Psum[(size_t)blockIdx.x * N_NODES + i0 + tid] = s;
    }
}

// ---------------------------------------------------------------------------
// k_v1: Vp[mc][n][d] = sum_{m in 64-chunk} EhatT[n,m] * inv[m] * U[m,d].
// 512 threads, grid (8 n-tiles x 256, 32 m-chunks) = 256 blocks x 8 waves.
// Wave = one d4 group (4 d); lane owns 4 n (il, il+64, il+128, il+192).
// Us read per m = same-address broadcast across the wave.
// nt==0 blocks also write U, inv, qpart.
// ---------------------------------------------------------------------------
__global__ __launch_bounds__(512) void k_v1(
    const __hip_bfloat16* __restrict__ EhatT, const float* __restrict__ Psum,
    const float* __restrict__ adj, const float* __restrict__ p,
    float* __restrict__ Vp, float* __restrict__ U, float* __restrict__ inv,
    float* __restrict__ qpart)
{
    __shared__ float Us[64 * 32];
    __shared__ float invL[64];
    __shared__ float red[512];
    const int tid = threadIdx.x;
    const int nt = blockIdx.x;      // 0..7
    const int mc = blockIdx.y;      // 0..31
    const int m0 = mc * 64;
    const int n0 = nt * 256;

    {   // row sums of Psum -> inv for rows m0..m0+63
        const int row = tid & 63, g = tid >> 6;      // g: 0..7, 4 t's each
        float s = 0.f;
#pragma unroll
        for (int t = 0; t < 4; t++)
            s += Psum[(size_t)(g * 4 + t) * N_NODES + m0 + row];
        red[tid] = s;
    }
    __syncthreads();
    if (tid < 64) {
        float t = 0.f;
#pragma unroll
        for (int gg = 0; gg < 8; gg++) t += red[gg * 64 + tid];
        const float iv = 1.0f / t;
        invL[tid] = iv;
        if (nt == 0) inv[m0 + tid] = iv;
    }
    __syncthreads();

    float qs = 0.f;
#pragma unroll
    for (int r = 0; r < 4; r++) {
        const int idx = r * 512 + tid;       // 0..2047
        const int row = idx >> 5;
        const float u = p[m0 + row] * adj[(size_t)m0 * EMBED + idx];
        Us[idx] = invL[row] * u;
        if (nt == 0) U[(size_t)m0 * EMBED + idx] = u;
        qs += u;                             // d = tid&31 fixed (512%32==0)
    }
    if (nt == 0) {
        __syncthreads();
        red[tid] = qs;
        __syncthreads();
        if (tid < 32) {
            float t = 0.f;
#pragma unroll
            for (int gg = 0; gg < 16; gg++) t += red[gg * 32 + tid];
            qpart[mc * EMBED + tid] = t;
        }
    }
    __syncthreads();

    const int il = tid & 63;
    const int d4 = (tid >> 6) * 4;   // wave-uniform: 0,4,..,28
    const uint4* Ev0 = (const uint4*)(EhatT + (size_t)(n0 + il      ) * N_NODES + m0);
    const uint4* Ev1 = (const uint4*)(EhatT + (size_t)(n0 + il +  64) * N_NODES + m0);
    const uint4* Ev2 = (const uint4*)(EhatT + (size_t)(n0 + il + 128) * N_NODES + m0);
    const uint4* Ev3 = (const uint4*)(EhatT + (size_t)(n0 + il + 192) * N_NODES + m0);
    float4 a0 = {}, a1 = {}, a2 = {}, a3 = {};
#pragma unroll
    for (int t = 0; t < 8; t++) {
        union { uint4 v; unsigned short s[8]; } p0, p1, p2, p3;
        p0.v = Ev0[t]; p1.v = Ev1[t]; p2.v = Ev2[t]; p3.v = Ev3[t];
#pragma unroll
        for (int j = 0; j < 8; j++) {
            const float4 u = *(const float4*)&Us[(t * 8 + j) * 32 + d4];  // broadcast
            const float e0 = __uint_as_float((unsigned)p0.s[j] << 16);
            const float e1 = __uint_as_float((unsigned)p1.s[j] << 16);
            const float e2 = __uint_as_float((unsigned)p2.s[j] << 16);
            const float e3 = __uint_as_float((unsigned)p3.s[j] << 16);
            a0.x += e0 * u.x; a0.y += e0 * u.y; a0.z += e0 * u.z; a0.w += e0 * u.w;
            a1.x += e1 * u.x; a1.y += e1 * u.y; a1.z += e1 * u.z; a1.w += e1 * u.w;
            a2.x += e2 * u.x; a2.y += e2 * u.y; a2.z += e2 * u.z; a2.w += e2 * u.w;
            a3.x += e3 * u.x; a3.y += e3 * u.y; a3.z += e3 * u.z; a3.w += e3 * u.w;
        }
    }
    float* Vb = Vp + (size_t)mc * (N_NODES * EMBED) + d4;
    *(float4*)(Vb + (size_t)(n0 + il      ) * EMBED) = a0;
    *(float4*)(Vb + (size_t)(n0 + il +  64) * EMBED) = a1;
    *(float4*)(Vb + (size_t)(n0 + il + 128) * EMBED) = a2;
    *(float4*)(Vb + (size_t)(n0 + il + 192) * EMBED) = a3;
}

// ---------------------------------------------------------------------------
// k_v2: same structure; Vp[mc][n][d] = sum_m EhatT[n,m] * V1p[m,d].
// ---------------------------------------------------------------------------
__global__ __launch_bounds__(512) void k_v2(
    const __hip_bfloat16* __restrict__ EhatT, const float* __restrict__ V1p,
    float* __restrict__ Vp)
{
    __shared__ float Us[64 * 32];
    const int tid = threadIdx.x;
    const int nt = blockIdx.x;
    const int mc = blockIdx.y;
    const int m0 = mc * 64;
    const int n0 = nt * 256;

#pragma unroll
    for (int r = 0; r < 4; r++) {
        const int idx = r * 512 + tid;
        Us[idx] = V1p[(size_t)m0 * EMBED + idx];
    }
    __syncthreads();

    const int il = tid & 63;
    const int d4 = (tid >> 6) * 4;
    const uint4* Ev0 = (const uint4*)(EhatT + (size_t)(n0 + il      ) * N_NODES + m0);
    const uint4* Ev1 = (const uint4*)(EhatT + (size_t)(n0 + il +  64) * N_NODES + m0);
    const uint4* Ev2 = (const uint4*)(EhatT + (size_t)(n0 + il + 128) * N_NODES + m0);
    const uint4* Ev3 = (const uint4*)(EhatT + (size_t)(n0 + il + 192) * N_NODES + m0);
    float4 a0 = {}, a1 = {}, a2 = {}, a3 = {};
#pragma unroll
    for (int t = 0; t < 8; t++) {
        union { uint4 v; unsigned short s[8]; } p0, p1, p2, p3;
        p0.v = Ev0[t]; p1.v = Ev1[t]; p2.v = Ev2[t]; p3.v = Ev3[t];
#pragma unroll
        for (int j = 0; j < 8; j++) {
            const float4 u = *(const float4*)&Us[(t * 8 + j) * 32 + d4];  // broadcast
            const float e0 = __uint_as_float((unsigned)p0.s[j] << 16);
            const float e1 = __uint_as_float((unsigned)p1.s[j] << 16);
            const float e2 = __uint_as_float((unsigned)p2.s[j] << 16);
            const float e3 = __uint_as_float((unsigned)p3.s[j] << 16);
            a0.x += e0 * u.x; a0.y += e0 * u.y; a0.z += e0 * u.z; a0.w += e0 * u.w;
            a1.x += e1 * u.x; a1.y += e1 * u.y; a1.z += e1 * u.z; a1.w += e1 * u.w;
            a2.x += e2 * u.x; a2.y += e2 * u.y; a2.z += e2 * u.z; a2.w += e2 * u.w;
            a3.x += e3 * u.x; a3.y += e3 * u.y; a3.z += e3 * u.z; a3.w += e3 * u.w;
        }
    }
    float* Vb = Vp + (size_t)mc * (N_NODES * EMBED) + d4;
    *(float4*)(Vb + (size_t)(n0 + il      ) * EMBED) = a0;
    *(float4*)(Vb + (size_t)(n0 + il +  64) * EMBED) = a1;
    *(float4*)(Vb + (size_t)(n0 + il + 128) * EMBED) = a2;
    *(float4*)(Vb + (size_t)(n0 + il + 192) * EMBED) = a3;
}

// ---------------------------------------------------------------------------
// k_vred: V[idx] = sum over 32 chunks; optionally Vprime = inv[row]*V.
// ---------------------------------------------------------------------------
__global__ __launch_bounds__(256) void k_vred(
    const float* __restrict__ Vp, const float* __restrict__ inv,
    float* __restrict__ V, float* __restrict__ Vprime, int writePrime)
{
    const int idx = blockIdx.x * 256 + threadIdx.x;   // 0..65535
    float s = 0.f;
#pragma unroll
    for (int c = 0; c < 32; c++) s += Vp[(size_t)c * (N_NODES * EMBED) + idx];
    V[idx] = s;
    if (writePrime) Vprime[idx] = inv[idx >> 5] * s;
}

// ---------------------------------------------------------------------------
// k_M: partials of M_k[d,c] = sum_n Vk[n,d] * X'[c,n], all k fused.
// grid (16 c-tiles x 32, 32 n-chunks x 64), 256 threads.
// ---------------------------------------------------------------------------
__global__ __launch_bounds__(256) void k_M(
    const float* __restrict__ XT, const float* __restrict__ V0,
    const float* __restrict__ V1, const float* __restrict__ V2,
    float* __restrict__ Mp)
{
    __shared__ float xs[32][65];
    __shared__ float vs[3][64 * 32];
    const int tid = threadIdx.x;
    const int c0 = blockIdx.x * 32;
    const int n0 = blockIdx.y * 64;
    const int d  = tid >> 3;
    const int cg = (tid & 7) * 4;

#pragma unroll
    for (int r = 0; r < 8; r++) {
        const int idx = r * 256 + tid;        // 0..2047
        xs[idx >> 6][idx & 63] = XT[(size_t)(c0 + (idx >> 6)) * N_NODES + n0 + (idx & 63)];
        vs[0][idx] = V0[(size_t)n0 * EMBED + idx];
        vs[1][idx] = V1[(size_t)n0 * EMBED + idx];
        vs[2][idx] = V2[(size_t)n0 * EMBED + idx];
    }
    __syncthreads();

    float acc[3][4] = {};
#pragma unroll 4
    for (int nn = 0; nn < 64; nn++) {
        const float v0 = vs[0][nn * 32 + d];
        const float v1 = vs[1][nn * 32 + d];
        const float v2 = vs[2][nn * 32 + d];
#pragma unroll
        for (int cc = 0; cc < 4; cc++) {
            const float xv = xs[cg + cc][nn];
            acc[0][cc] += xv * v0;
            acc[1][cc] += xv * v1;
            acc[2][cc] += xv * v2;
        }
    }
#pragma unroll
    for (int k = 0; k < 3; k++) {
        float* dst = Mp + ((size_t)(blockIdx.y * 3 + k) * EMBED + d) * NCOL + c0 + cg;
        *(float4*)dst = make_float4(acc[k][0], acc[k][1], acc[k][2], acc[k][3]);
    }
}

// ---------------------------------------------------------------------------
// k_Mred: coalesced reduction of Mp chunks -> M (49152 floats). 192 blocks.
// ---------------------------------------------------------------------------
__global__ __launch_bounds__(256) void k_Mred(
    const float* __restrict__ Mp, float* __restrict__ M)
{
    const int idx = blockIdx.x * 256 + threadIdx.x;   // 0..49151
    float s = 0.f;
#pragma unroll
    for (int c = 0; c < 32; c++)
        s += Mp[(size_t)c * (CHEB_K * EMBED * NCOL) + idx];
    M[idx] = s;
}

// ---------------------------------------------------------------------------
// k_final: 128 blocks = (d 0..31) x (o-group 0..3). Tiny M[d] + L2-resident W;
// atomicAdd d-partials into zeroed out (16K atomics total - fine).
// ---------------------------------------------------------------------------
__global__ __launch_bounds__(256) void k_final(
    const float* __restrict__ M, const float* __restrict__ W,
    const float* __restrict__ bp, const float* __restrict__ qpart,
    const float* __restrict__ pb, float* __restrict__ out)
{
    const int d  = blockIdx.x >> 2;
    const int og = (blockIdx.x & 3) * 8;
    const int tid = threadIdx.x;
    __shared__ float mL[3 * 512];
    __shared__ float qL[32];

#pragma unroll
    for (int r = 0; r < 6; r++) {
        const int e = r * 256 + tid;             // 0..1535
        mL[e] = M[(size_t)((e >> 9) * EMBED + d) * NCOL + (e & 511)];
    }
    if (d == 0 && tid < 32) {
        float s = 0.f;
#pragma unroll
        for (int mc = 0; mc < 32; mc++) s += qpart[mc * EMBED + tid];
        qL[tid] = s;
    }
    __syncthreads();

    if (tid < 128) {
        const int b = tid >> 3;
        const int o = og + (tid & 7);
        float acc = 0.f;
#pragma unroll
        for (int i = 0; i < 32; i++) {
            const float m0 = mL[b * 32 + i];
            const float m1 = mL[512 + b * 32 + i];
            const float m2 = mL[1024 + b * 32 + i];
            const float w0 = W[((size_t)(d * 3 + 0) * 32 + i) * 32 + o];
            const float w1 = W[((size_t)(d * 3 + 1) * 32 + i) * 32 + o];
            const float w2 = W[((size_t)(d * 3 + 2) * 32 + i) * 32 + o];
            acc += m0 * (w0 - w2) + m1 * w1 + 2.f * m2 * w2;
        }
        if (d == 0) {
            float bias = pb[0];
#pragma unroll
            for (int dd = 0; dd < 32; dd++) bias += qL[dd] * bp[dd * OUTC + o];
            acc += bias;
        }
        atomicAdd(&out[b * OUTC + o], acc);
    }
}

// ---------------------------------------------------------------------------
extern "C" void kernel_launch(void* const* d_in, const int* in_sizes, int n_in,
                              void* d_out, int out_size, void* d_ws, size_t ws_size,
                              hipStream_t stream)
{
    const float* x     = (const float*)d_in[0];
    const float* adj   = (const float*)d_in[1];
    const float* gamma = (const float*)d_in[2];
    const float* Wp    = (const float*)d_in[3];
    const float* bp    = (const float*)d_in[4];
    const float* pw    = (const float*)d_in[5];
    const float* pb    = (const float*)d_in[6];
    const float* drop  = (const float*)d_in[7];
    float* out = (float*)d_out;

    float* ws = (float*)d_ws;
    __hip_bfloat16* EhatT = (__hip_bfloat16*)ws;              // 8 MB (4M bf16)
    float* Vp    = ws   + (size_t)N_NODES * N_NODES / 2;      // 8 MB (32 chunks)
    float* Mp    = Vp;                                        // alias (Vp dead after vred2)
    float* Psum  = Vp   + (size_t)32 * N_NODES * EMBED;       // 256 KB
    float* inv   = Psum + (size_t)32 * N_NODES;               // 8 KB
    float* U     = inv  + N_NODES;                            // 256 KB
    float* V1    = U    + (size_t)N_NODES * EMBED;            // 256 KB
    float* V1p   = V1   + (size_t)N_NODES * EMBED;            // 256 KB
    float* V2    = V1p  + (size_t)N_NODES * EMBED;            // 256 KB
    float* M     = V2   + (size_t)N_NODES * EMBED;            // 192 KB
    float* qpart = M    + (size_t)CHEB_K * EMBED * NCOL;      // 4 KB

    k_gram<<<dim3(32, 32), 256, 0, stream>>>(adj, gamma, drop, EhatT, Psum, out);

    dim3 gv(8, 32);
    k_v1<<<gv, 512, 0, stream>>>(EhatT, Psum, adj, pw, Vp, U, inv, qpart);
    k_vred<<<256, 256, 0, stream>>>(Vp, inv, V1, V1p, 1);
    k_v2<<<gv, 512, 0, stream>>>(EhatT, V1p, Vp);
    k_vred<<<256, 256, 0, stream>>>(Vp, inv, V2, V2, 0);

    k_M<<<dim3(16, 32), 256, 0, stream>>>(x, U, V1, V2, Mp);
    k_Mred<<<192, 256, 0, stream>>>(Mp, M);
    k_final<<<128, 256, 0, stream>>>(M, Wp, bp, qpart, pb, out);
}

// Round 17
// 128.522 us; speedup vs baseline: 1.0721x; 1.0721x over previous
//
#include <hip/hip_runtime.h>
#include <hip/hip_bf16.h>

// Problem constants (fixed by reference)
#define N_NODES 2048
#define EMBED   32
#define B_BATCH 16
#define INP     32
#define OUTC    32
#define CHEB_K  3
#define NCOL    512

// R17 = R15 verbatim (measured best: 130.8us, absmax 0.031).
// R16 post-mortem: k_v broadcast restructure (+7us) falsified the LDS-BW
// theory; k_v sits at its latency/issue floor. Experiment ledger around the
// ~131us plateau: bf16 Ehat -1.0, EhatT transpose -0.4, chunk-halving +8,
// LDS-broadcast +7, persistent fusion +80..+520, bulk atomics +218.
// Structure: 8 dispatches; ~43us is the harness's fixed 268MB ws re-poison
// fill; remaining ~88us = 8 launch/drain floors + latency-bound tails over
// ~15-20us of pure roofline work. All structural alternatives measured worse.
// LAW (R13): never trade blocks/CU for traffic on latency-bound kernels.
// LAW (R9/R11): no bulk global fp32 atomicAdd (uncached 32B RMW at MALL).
// LAW (R7-R9): no software grid barrier; dispatch boundaries are cheaper.

// ---------------------------------------------------------------------------
// k_gram: 64x64 tiles. EhatT[j][i] = bf16(exp(exp(-g*dist(i,j)))*drop[i][j]),
// Psum[jt][i] = fp32 row-sum partials (pre-drop). Block (0,0) zeroes out.
// ---------------------------------------------------------------------------
__global__ __launch_bounds__(256) void k_gram(
    const float* __restrict__ adj, const float* __restrict__ gammap,
    const float* __restrict__ drop,
    __hip_bfloat16* __restrict__ EhatT, float* __restrict__ Psum,
    float* __restrict__ out)
{
    __shared__ float ai[64][36];            // [row i][k]
    __shared__ float ajT[32][68];           // [k][col j]
    __shared__ float nI[64], nJ[64];
    __shared__ float rm[64][17];
    __shared__ __hip_bfloat16 tS[64][72];   // [local j][local i]
    const int tid = threadIdx.x;
    if (blockIdx.x == 0 && blockIdx.y == 0) {
        out[tid] = 0.f; out[256 + tid] = 0.f;
    }
    const int j0 = blockIdx.x * 64;
    const int i0 = blockIdx.y * 64;
    const float gamma = gammap[0];

#pragma unroll
    for (int r = 0; r < 8; r++) {
        const int idx = r * 256 + tid;           // 0..2047
        ai[idx >> 5][idx & 31]  = adj[(size_t)(i0 + (idx >> 5)) * EMBED + (idx & 31)];
        ajT[idx & 31][idx >> 5] = adj[(size_t)(j0 + (idx >> 5)) * EMBED + (idx & 31)];
    }
    __syncthreads();
    if (tid < 64) {
        float s = 0.f;
#pragma unroll
        for (int k = 0; k < 32; k++) { const float v = ai[tid][k]; s += v * v; }
        nI[tid] = s;
    } else if (tid < 128) {
        const int col = tid - 64;
        float s = 0.f;
#pragma unroll
        for (int k = 0; k < 32; k++) { const float v = ajT[k][col]; s += v * v; }
        nJ[col] = s;
    }
    __syncthreads();

    const int ti = tid >> 4, tj = tid & 15;
    float acc[4][4] = {};
#pragma unroll
    for (int k4 = 0; k4 < 8; k4++) {
        float4 a4[4], b4[4];
#pragma unroll
        for (int r = 0; r < 4; r++) a4[r] = *(const float4*)&ai[ti * 4 + r][k4 * 4];
#pragma unroll
        for (int kk = 0; kk < 4; kk++) b4[kk] = *(const float4*)&ajT[k4 * 4 + kk][tj * 4];
#pragma unroll
        for (int r = 0; r < 4; r++) {
            acc[r][0] += a4[r].x * b4[0].x + a4[r].y * b4[1].x + a4[r].z * b4[2].x + a4[r].w * b4[3].x;
            acc[r][1] += a4[r].x * b4[0].y + a4[r].y * b4[1].y + a4[r].z * b4[2].y + a4[r].w * b4[3].y;
            acc[r][2] += a4[r].x * b4[0].z + a4[r].y * b4[1].z + a4[r].z * b4[2].z + a4[r].w * b4[3].z;
            acc[r][3] += a4[r].x * b4[0].w + a4[r].y * b4[1].w + a4[r].z * b4[2].w + a4[r].w * b4[3].w;
        }
    }
#pragma unroll
    for (int r = 0; r < 4; r++) {
        const int i = i0 + ti * 4 + r;
        const float ni = nI[ti * 4 + r];
        float e[4];
#pragma unroll
        for (int c = 0; c < 4; c++) {
            const float dist = ni + nJ[tj * 4 + c] - 2.f * acc[r][c];
            e[c] = __expf(__expf(-gamma * dist));
        }
        rm[ti * 4 + r][tj] = e[0] + e[1] + e[2] + e[3];
        const float4 dr = *(const float4*)&drop[(size_t)i * N_NODES + j0 + tj * 4];
        tS[tj * 4 + 0][ti * 4 + r] = __float2bfloat16(e[0] * dr.x);
        tS[tj * 4 + 1][ti * 4 + r] = __float2bfloat16(e[1] * dr.y);
        tS[tj * 4 + 2][ti * 4 + r] = __float2bfloat16(e[2] * dr.z);
        tS[tj * 4 + 3][ti * 4 + r] = __float2bfloat16(e[3] * dr.w);
    }
    __syncthreads();
    {   // coalesced transposed write-out: 4 threads per row j, 16 cols each
        const int jr = tid >> 2;            // 0..63
        const int ic = (tid & 3) * 16;      // 0,16,32,48
        const uint4* src = (const uint4*)&tS[jr][ic];
        uint4* dst = (uint4*)(EhatT + (size_t)(j0 + jr) * N_NODES + i0 + ic);
        dst[0] = src[0];
        dst[1] = src[1];
    }
    if (tid < 64) {
        float s = 0.f;
#pragma unroll
        for (int t = 0; t < 16; t++) s += rm[tid][t];
        Psum[(size_t)blockIdx.x * N_NODES + i0 + tid] = s;
    }
}

// ---------------------------------------------------------------------------
// k_v1: Vp[mc][n][d] = sum_{m in 64-chunk} EhatT[n,m] * inv[m] * U[m,d].
// inv recomputed per block from Psum; nt==0 blocks write U, inv, qpart.
// grid (16 n-tiles x 128, 32 m-chunks x 64) = 512 blocks.
// Ehat read: one uint4 (8 bf16) per lane per 8-m group, per-lane contiguous.
// ---------------------------------------------------------------------------
__global__ __launch_bounds__(256) void k_v1(
    const __hip_bfloat16* __restrict__ EhatT, const float* __restrict__ Psum,
    const float* __restrict__ adj, const float* __restrict__ p,
    float* __restrict__ Vp, float* __restrict__ U, float* __restrict__ inv,
    float* __restrict__ qpart)
{
    __shared__ float Us[64 * 32];
    __shared__ float invL[64];
    __shared__ float red[256];
    const int tid = threadIdx.x;
    const int nt = blockIdx.x;
    const int mc = blockIdx.y;
    const int m0 = mc * 64;

    {   // row sums of Psum -> inv for rows m0..m0+63
        const int row = tid & 63, g = tid >> 6;      // g: 0..3, 8 t's each
        float s = 0.f;
#pragma unroll
        for (int t = 0; t < 8; t++)
            s += Psum[(size_t)(g * 8 + t) * N_NODES + m0 + row];
        red[tid] = s;
    }
    __syncthreads();
    if (tid < 64) {
        const float iv = 1.0f / (red[tid] + red[64 + tid] + red[128 + tid] + red[192 + tid]);
        invL[tid] = iv;
        if (nt == 0) inv[m0 + tid] = iv;
    }
    __syncthreads();

    float qs = 0.f;
#pragma unroll
    for (int r = 0; r < 8; r++) {
        const int idx = r * 256 + tid;       // 0..2047
        const int row = idx >> 5;
        const float u = p[m0 + row] * adj[(size_t)m0 * EMBED + idx];
        Us[idx] = invL[row] * u;
        if (nt == 0) U[(size_t)m0 * EMBED + idx] = u;
        qs += u;                             // d = tid&31 fixed per thread
    }
    if (nt == 0) {
        __syncthreads();
        red[tid] = qs;
        __syncthreads();
        if (tid < 32) {
            float t = 0.f;
#pragma unroll
            for (int gg = 0; gg < 8; gg++) t += red[gg * 32 + tid];
            qpart[mc * EMBED + tid] = t;
        }
    }
    __syncthreads();

    const int n  = nt * 128 + (tid & 127);
    const int dh = (tid >> 7) * 16;
    const uint4* Ev = (const uint4*)(EhatT + (size_t)n * N_NODES + m0);  // 8 uint4 = 64 bf16
    float4 a0 = {}, a1 = {}, a2 = {}, a3 = {};
#pragma unroll
    for (int t = 0; t < 8; t++) {
        union { uint4 v; unsigned short s[8]; } pk;
        pk.v = Ev[t];
        float e[8];
#pragma unroll
        for (int j = 0; j < 8; j++) e[j] = __uint_as_float((unsigned)pk.s[j] << 16);
#pragma unroll
        for (int j = 0; j < 8; j++) {
            const float4* u4 = (const float4*)&Us[(t * 8 + j) * 32 + dh];
            const float4 u0 = u4[0], u1 = u4[1], u2 = u4[2], u3 = u4[3];
            a0.x += e[j] * u0.x; a0.y += e[j] * u0.y; a0.z += e[j] * u0.z; a0.w += e[j] * u0.w;
            a1.x += e[j] * u1.x; a1.y += e[j] * u1.y; a1.z += e[j] * u1.z; a1.w += e[j] * u1.w;
            a2.x += e[j] * u2.x; a2.y += e[j] * u2.y; a2.z += e[j] * u2.z; a2.w += e[j] * u2.w;
            a3.x += e[j] * u3.x; a3.y += e[j] * u3.y; a3.z += e[j] * u3.z; a3.w += e[j] * u3.w;
        }
    }
    float4* o = (float4*)(Vp + (size_t)mc * (N_NODES * EMBED) + (size_t)n * EMBED + dh);
    o[0] = a0; o[1] = a1; o[2] = a2; o[3] = a3;
}

// ---------------------------------------------------------------------------
// k_v2: Vp[mc][n][d] = sum_{m in 64-chunk} EhatT[n,m] * V1p[m,d] (inv folded).
// ---------------------------------------------------------------------------
__global__ __launch_bounds__(256) void k_v2(
    const __hip_bfloat16* __restrict__ EhatT, const float* __restrict__ V1p,
    float* __restrict__ Vp)
{
    __shared__ float Us[64 * 32];
    const int tid = threadIdx.x;
    const int n  = blockIdx.x * 128 + (tid & 127);
    const int dh = (tid >> 7) * 16;
    const int m0 = blockIdx.y * 64;

#pragma unroll
    for (int r = 0; r < 8; r++) {
        const int idx = r * 256 + tid;
        Us[idx] = V1p[(size_t)m0 * EMBED + idx];
    }
    __syncthreads();

    const uint4* Ev = (const uint4*)(EhatT + (size_t)n * N_NODES + m0);
    float4 a0 = {}, a1 = {}, a2 = {}, a3 = {};
#pragma unroll
    for (int t = 0; t < 8; t++) {
        union { uint4 v; unsigned short s[8]; } pk;
        pk.v = Ev[t];
        float e[8];
#pragma unroll
        for (int j = 0; j < 8; j++) e[j] = __uint_as_float((unsigned)pk.s[j] << 16);
#pragma unroll
        for (int j = 0; j < 8; j++) {
            const float4* u4 = (const float4*)&Us[(t * 8 + j) * 32 + dh];
            const float4 u0 = u4[0], u1 = u4[1], u2 = u4[2], u3 = u4[3];
            a0.x += e[j] * u0.x; a0.y += e[j] * u0.y; a0.z += e[j] * u0.z; a0.w += e[j] * u0.w;
            a1.x += e[j] * u1.x; a1.y += e[j] * u1.y; a1.z += e[j] * u1.z; a1.w += e[j] * u1.w;
            a2.x += e[j] * u2.x; a2.y += e[j] * u2.y; a2.z += e[j] * u2.z; a2.w += e[j] * u2.w;
            a3.x += e[j] * u3.x; a3.y += e[j] * u3.y; a3.z += e[j] * u3.z; a3.w += e[j] * u3.w;
        }
    }
    float4* o = (float4*)(Vp + (size_t)blockIdx.y * (N_NODES * EMBED) + (size_t)n * EMBED + dh);
    o[0] = a0; o[1] = a1; o[2] = a2; o[3] = a3;
}

// ---------------------------------------------------------------------------
// k_vred: V[idx] = sum over 32 chunks; optionally Vprime = inv[row]*V.
// ---------------------------------------------------------------------------
__global__ __launch_bounds__(256) void k_vred(
    const float* __restrict__ Vp, const float* __restrict__ inv,
    float* __restrict__ V, float* __restrict__ Vprime, int writePrime)
{
    const int idx = blockIdx.x * 256 + threadIdx.x;   // 0..65535
    float s = 0.f;
#pragma unroll
    for (int c = 0; c < 32; c++) s += Vp[(size_t)c * (N_NODES * EMBED) + idx];
    V[idx] = s;
    if (writePrime) Vprime[idx] = inv[idx >> 5] * s;
}

// ---------------------------------------------------------------------------
// k_M: partials of M_k[d,c] = sum_n Vk[n,d] * X'[c,n], all k fused.
// grid (16 c-tiles x 32, 32 n-chunks x 64), 256 threads.
// ---------------------------------------------------------------------------
__global__ __launch_bounds__(256) void k_M(
    const float* __restrict__ XT, const float* __restrict__ V0,
    const float* __restrict__ V1, const float* __restrict__ V2,
    float* __restrict__ Mp)
{
    __shared__ float xs[32][65];
    __shared__ float vs[3][64 * 32];
    const int tid = threadIdx.x;
    const int c0 = blockIdx.x * 32;
    const int n0 = blockIdx.y * 64;
    const int d  = tid >> 3;
    const int cg = (tid & 7) * 4;

#pragma unroll
    for (int r = 0; r < 8; r++) {
        const int idx = r * 256 + tid;        // 0..2047
        xs[idx >> 6][idx & 63] = XT[(size_t)(c0 + (idx >> 6)) * N_NODES + n0 + (idx & 63)];
        vs[0][idx] = V0[(size_t)n0 * EMBED + idx];
        vs[1][idx] = V1[(size_t)n0 * EMBED + idx];
        vs[2][idx] = V2[(size_t)n0 * EMBED + idx];
    }
    __syncthreads();

    float acc[3][4] = {};
#pragma unroll 4
    for (int nn = 0; nn < 64; nn++) {
        const float v0 = vs[0][nn * 32 + d];
        const float v1 = vs[1][nn * 32 + d];
        const float v2 = vs[2][nn * 32 + d];
#pragma unroll
        for (int cc = 0; cc < 4; cc++) {
            const float xv = xs[cg + cc][nn];
            acc[0][cc] += xv * v0;
            acc[1][cc] += xv * v1;
            acc[2][cc] += xv * v2;
        }
    }
#pragma unroll
    for (int k = 0; k < 3; k++) {
        float* dst = Mp + ((size_t)(blockIdx.y * 3 + k) * EMBED + d) * NCOL + c0 + cg;
        *(float4*)dst = make_float4(acc[k][0], acc[k][1], acc[k][2], acc[k][3]);
    }
}

// ---------------------------------------------------------------------------
// k_Mred: coalesced reduction of Mp chunks -> M (49152 floats). 192 blocks.
// ---------------------------------------------------------------------------
__global__ __launch_bounds__(256) void k_Mred(
    const float* __restrict__ Mp, float* __restrict__ M)
{
    const int idx = blockIdx.x * 256 + threadIdx.x;   // 0..49151
    float s = 0.f;
#pragma unroll
    for (int c = 0; c < 32; c++)
        s += Mp[(size_t)c * (CHEB_K * EMBED * NCOL) + idx];
    M[idx] = s;
}

// ---------------------------------------------------------------------------
// k_final: 128 blocks = (d 0..31) x (o-group 0..3). Tiny M[d] + L2-resident W;
// atomicAdd d-partials into zeroed out (16K atomics total - fine).
// ---------------------------------------------------------------------------
__global__ __launch_bounds__(256) void k_final(
    const float* __restrict__ M, const float* __restrict__ W,
    const float* __restrict__ bp, const float* __restrict__ qpart,
    const float* __restrict__ pb, float* __restrict__ out)
{
    const int d  = blockIdx.x >> 2;
    const int og = (blockIdx.x & 3) * 8;
    const int tid = threadIdx.x;
    __shared__ float mL[3 * 512];
    __shared__ float qL[32];

#pragma unroll
    for (int r = 0; r < 6; r++) {
        const int e = r * 256 + tid;             // 0..1535
        mL[e] = M[(size_t)((e >> 9) * EMBED + d) * NCOL + (e & 511)];
    }
    if (d == 0 && tid < 32) {
        float s = 0.f;
#pragma unroll
        for (int mc = 0; mc < 32; mc++) s += qpart[mc * EMBED + tid];
        qL[tid] = s;
    }
    __syncthreads();

    if (tid < 128) {
        const int b = tid >> 3;
        const int o = og + (tid & 7);
        float acc = 0.f;
#pragma unroll
        for (int i = 0; i < 32; i++) {
            const float m0 = mL[b * 32 + i];
            const float m1 = mL[512 + b * 32 + i];
            const float m2 = mL[1024 + b * 32 + i];
            const float w0 = W[((size_t)(d * 3 + 0) * 32 + i) * 32 + o];
            const float w1 = W[((size_t)(d * 3 + 1) * 32 + i) * 32 + o];
            const float w2 = W[((size_t)(d * 3 + 2) * 32 + i) * 32 + o];
            acc += m0 * (w0 - w2) + m1 * w1 + 2.f * m2 * w2;
        }
        if (d == 0) {
            float bias = pb[0];
#pragma unroll
            for (int dd = 0; dd < 32; dd++) bias += qL[dd] * bp[dd * OUTC + o];
            acc += bias;
        }
        atomicAdd(&out[b * OUTC + o], acc);
    }
}

// ---------------------------------------------------------------------------
extern "C" void kernel_launch(void* const* d_in, const int* in_sizes, int n_in,
                              void* d_out, int out_size, void* d_ws, size_t ws_size,
                              hipStream_t stream)
{
    const float* x     = (const float*)d_in[0];
    const float* adj   = (const float*)d_in[1];
    const float* gamma = (const float*)d_in[2];
    const float* Wp    = (const float*)d_in[3];
    const float* bp    = (const float*)d_in[4];
    const float* pw    = (const float*)d_in[5];
    const float* pb    = (const float*)d_in[6];
    const float* drop  = (const float*)d_in[7];
    float* out = (float*)d_out;

    float* ws = (float*)d_ws;
    __hip_bfloat16* EhatT = (__hip_bfloat16*)ws;              // 8 MB (4M bf16)
    float* Vp    = ws   + (size_t)N_NODES * N_NODES / 2;      // 8 MB (32 chunks)
    float* Mp    = Vp;                                        // alias (Vp dead after vred2)
    float* Psum  = Vp   + (size_t)32 * N_NODES * EMBED;       // 256 KB
    float* inv   = Psum + (size_t)32 * N_NODES;               // 8 KB
    float* U     = inv  + N_NODES;                            // 256 KB
    float* V1    = U    + (size_t)N_NODES * EMBED;            // 256 KB
    float* V1p   = V1   + (size_t)N_NODES * EMBED;            // 256 KB
    float* V2    = V1p  + (size_t)N_NODES * EMBED;            // 256 KB
    float* M     = V2   + (size_t)N_NODES * EMBED;            // 192 KB
    float* qpart = M    + (size_t)CHEB_K * EMBED * NCOL;      // 4 KB

    k_gram<<<dim3(32, 32), 256, 0, stream>>>(adj, gamma, drop, EhatT, Psum, out);

    dim3 gv(16, 32);
    k_v1<<<gv, 256, 0, stream>>>(EhatT, Psum, adj, pw, Vp, U, inv, qpart);
    k_vred<<<256, 256, 0, stream>>>(Vp, inv, V1, V1p, 1);
    k_v2<<<gv, 256, 0, stream>>>(EhatT, V1p, Vp);
    k_vred<<<256, 256, 0, stream>>>(Vp, inv, V2, V2, 0);

    k_M<<<dim3(16, 32), 256, 0, stream>>>(x, U, V1, V2, Mp);
    k_Mred<<<192, 256, 0, stream>>>(Mp, M);
    k_final<<<128, 256, 0, stream>>>(M, Wp, bp, qpart, pb, out);
}